// Round 20
// baseline (68.766 us; speedup 1.0000x reference)
//
#include <hip/hip_runtime.h>
#include <hip/hip_bf16.h>

#define SEQ 2048
#define HD 64
#define NBH 32
#define SCALE 0.125f
#define QSC 0.18033688011112042f   // 0.125 * log2(e)  -> softmax in exp2 domain

typedef __attribute__((ext_vector_type(4)))  float    f32x4;
typedef __attribute__((ext_vector_type(16))) float    f32x16;
typedef __attribute__((ext_vector_type(8)))  short    bf16x8;
typedef __attribute__((ext_vector_type(4)))  unsigned u32x4;

__device__ inline short f2bf(float f) {
    unsigned u = __builtin_bit_cast(unsigned, f);
    unsigned r = u + 0x7FFFu + ((u >> 16) & 1u);
    return (short)(r >> 16);
}

__device__ inline unsigned cvt2(float lo, float hi) {
    unsigned d;
    asm("v_cvt_pk_bf16_f32 %0, %1, %2" : "=v"(d) : "v"(lo), "v"(hi));
    return d;
}

// Detect mask element size (1-byte bool vs 4-byte), for the r1 fallback path only.
__global__ void detect_mask_kernel(const unsigned char* __restrict__ m, int n, int* flag) {
    if (threadIdx.x == 0) *flag = (m[n - 1] != 0) ? 1 : 4;
}

// Fused prepass (validated r12/r16). Also zeroes the work-steal counter.
// [0,512):    bitpack mask -> bitsT[64][2048]
// [512,2560): K fp32 -> bf16 granule-major tiles (wave frag = stride-16B linear)
// [2560,3584): V fp32 -> Vt granule-major with swap23 k-relabel
__global__ __launch_bounds__(256)
void prep_kernel(const unsigned char* __restrict__ m, int mn,
                 const float* __restrict__ K, const float* __restrict__ V,
                 unsigned* __restrict__ bits, short* __restrict__ Kb,
                 short* __restrict__ Vt, int* __restrict__ ctr) {
    __shared__ short t[64][65];
    const int b = blockIdx.x, tid = threadIdx.x;
    if (b == 0 && tid == 0) *ctr = 0;   // reset work-steal counter every launch
    if (b < 512) {
        const bool e1 = (m[mn - 1] != 0);
        const int idx = b * 256 + tid;
        const int row = idx >> 6, w = idx & 63;
        const size_t base = (size_t)row * SEQ + w * 32;
        unsigned word = 0;
        if (e1) {
            #pragma unroll
            for (int i = 0; i < 32; ++i) word |= (unsigned)(m[base + i] != 0) << i;
        } else {
            const unsigned* m32 = (const unsigned*)m;
            #pragma unroll
            for (int i = 0; i < 32; ++i) word |= (unsigned)(m32[base + i] != 0) << i;
        }
        bits[(size_t)w * SEQ + row] = word;
    } else if (b < 2560) {
        const int g = (b - 512) * 256 + tid;     // granule index
        const size_t i = (size_t)g * 8;
        f32x4 a = *(const f32x4*)(K + i);
        f32x4 c = *(const f32x4*)(K + i + 4);
        bf16x8 o;
        #pragma unroll
        for (int j = 0; j < 4; ++j) { o[j] = f2bf(a[j]); o[4 + j] = f2bf(c[j]); }
        const int row = g >> 3;
        const int c8  = g & 7;
        const int bh  = row >> 11;
        const int r   = row & 2047;
        const int tt  = r >> 5;
        const int la  = r & 31;
        *(bf16x8*)(Kb + ((size_t)bh * 64 + tt) * 2048 + (c8 * 32 + la) * 8) = o;
    } else {
        const int bb = b - 2560;
        const int s0 = (bb & 31) * 64, bh = bb >> 5;
        const float* Vb = V + (size_t)bh * SEQ * HD;
        const int sr = tid >> 6, d = tid & 63;
        #pragma unroll
        for (int i = 0; i < 16; ++i) {
            const int s = i * 4 + sr;
            t[s][d] = f2bf(Vb[(size_t)(s0 + s) * HD + d]);
        }
        __syncthreads();
        short* o = Vt + (size_t)bh * HD * SEQ;
        const int dr = tid >> 6, sl = tid & 63;
        #pragma unroll
        for (int i = 0; i < 16; ++i) {
            const int dd = i * 4 + dr;
            const int s = s0 + sl;
            const int k = s & 31;
            const int p = (k & ~12) | ((k & 8) >> 1) | ((k & 4) << 1);   // swap bits 2,3
            const int mm = ((dd >> 5) << 1) | (p >> 4);
            const int hh = (p >> 3) & 1;
            o[(size_t)(s >> 5) * 2048 + ((mm * 2 + hh) * 32 + (dd & 31)) * 8 + (p & 7)] = t[sl][dd];
        }
    }
}

// ================= persistent work-stealing monolith (r20) =================
// r19's proven body (2-tile windows, shared-KV double-buffered staging, fixed
// scale softmax, zero-cross-lane P-pack, aliased 32KB pool, dependent 4-MFMA
// QK chain). NEW: 512 PERSISTENT blocks grab work items from a global atomic
// counter, heavy-first (item u -> qg=15-(u>>5), bh=u&31). Static "balanced
// pairing" assumed round-robin block->CU dispatch -- which is UNDEFINED; the
// measured occupancy decay (13.9% vs 25% static) is the imbalance tail.
// Dynamic stealing self-balances under ANY dispatch order: blocks finishing
// light items loop back for more while heavy items (grabbed first) run long.
__global__ __launch_bounds__(256, 2)
void attn_persist_kernel(const float* __restrict__ Q, const short* __restrict__ Kb,
                         const short* __restrict__ Vt, const unsigned* __restrict__ bitsT,
                         int* __restrict__ ctr, float* __restrict__ Out) {
    __shared__ __align__(16) short pool[16384];   // 32KB: kv staging, then oacc alias
    __shared__ int sitem;
    short* kpool = pool;              // buf stride 4096, tile stride 2048
    short* vpool = pool + 8192;

    const int tid  = threadIdx.x;
    const int wid  = tid >> 6;
    const int lane = tid & 63;
    const int la   = lane & 31;
    const int h    = lane >> 5;
    const int bp   = 4 * h;

    for (;;) {
        if (tid == 0) sitem = atomicAdd(ctr, 1);
        __syncthreads();
        const int u = sitem;
        if (u >= 512) break;

        const int bh = u & 31;
        const int qg = 15 - (u >> 5);          // heavy items grabbed first
        const int q0w = qg * 128 + wid * 32;
        const int nt  = qg * 4 + 4;            // multiple of 4
        const size_t base = (size_t)bh * SEQ * HD;

        // Q as MFMA B-operand: col=q=la, k-elem i of chunk j -> d = j*16+h*8+i
        bf16x8 qf[4];
        {
            const float* qp = Q + base + (size_t)(q0w + la) * HD + h * 8;
            #pragma unroll
            for (int j = 0; j < 4; ++j) {
                f32x4 a0 = *(const f32x4*)(qp + j * 16);
                f32x4 a1 = *(const f32x4*)(qp + j * 16 + 4);
                #pragma unroll
                for (int i = 0; i < 4; ++i) {
                    qf[j][i]     = f2bf(a0[i] * QSC);
                    qf[j][4 + i] = f2bf(a1[i] * QSC);
                }
            }
        }

        f32x16 acc_o0 = {0,0,0,0,0,0,0,0,0,0,0,0,0,0,0,0};
        f32x16 acc_o1 = {0,0,0,0,0,0,0,0,0,0,0,0,0,0,0,0};
        float l_run = 0.f;

        const short* Ktg = Kb + (size_t)bh * 64 * 2048;
        const short* Vtg = Vt + (size_t)bh * 64 * 2048;
        const unsigned* bq = bitsT + q0w + la;

        auto body = [&](const short* kb, const short* vb, unsigned mwx) {
            bf16x8 kfa = *(const bf16x8*)(kb + lane * 8);
            bf16x8 kfb = *(const bf16x8*)(kb + 512 + lane * 8);
            bf16x8 kfc = *(const bf16x8*)(kb + 1024 + lane * 8);
            bf16x8 kfd = *(const bf16x8*)(kb + 1536 + lane * 8);
            bf16x8 vf00 = *(const bf16x8*)(vb + lane * 8);
            bf16x8 vf01 = *(const bf16x8*)(vb + 512 + lane * 8);
            bf16x8 vf10 = *(const bf16x8*)(vb + 1024 + lane * 8);
            bf16x8 vf11 = *(const bf16x8*)(vb + 1536 + lane * 8);

            f32x16 s = {0,0,0,0,0,0,0,0,0,0,0,0,0,0,0,0};
            __builtin_amdgcn_s_setprio(1);
            s = __builtin_amdgcn_mfma_f32_32x32x16_bf16(kfa, qf[0], s, 0, 0, 0);
            s = __builtin_amdgcn_mfma_f32_32x32x16_bf16(kfb, qf[1], s, 0, 0, 0);
            s = __builtin_amdgcn_mfma_f32_32x32x16_bf16(kfc, qf[2], s, 0, 0, 0);
            s = __builtin_amdgcn_mfma_f32_32x32x16_bf16(kfd, qf[3], s, 0, 0, 0);
            __builtin_amdgcn_s_setprio(0);

            #pragma unroll
            for (int r = 0; r < 16; ++r) {
                float e = __builtin_amdgcn_exp2f(s[r]);
                s[r] = ((mwx >> (bp + (r & 3) + 8 * (r >> 2))) & 1u) ? e : 0.f;
            }
            float ps = ((s[0] + s[1]) + (s[2] + s[3])) + ((s[4] + s[5]) + (s[6] + s[7]));
            ps += ((s[8] + s[9]) + (s[10] + s[11])) + ((s[12] + s[13]) + (s[14] + s[15]));
            l_run += ps;

            u32x4 t1 = {cvt2(s[0], s[1]),  cvt2(s[2], s[3]),
                        cvt2(s[4], s[5]),  cvt2(s[6], s[7])};
            u32x4 t2 = {cvt2(s[8], s[9]),  cvt2(s[10], s[11]),
                        cvt2(s[12], s[13]), cvt2(s[14], s[15])};
            bf16x8 pb1 = __builtin_bit_cast(bf16x8, t1);
            bf16x8 pb2 = __builtin_bit_cast(bf16x8, t2);

            __builtin_amdgcn_s_setprio(1);
            acc_o0 = __builtin_amdgcn_mfma_f32_32x32x16_bf16(vf00, pb1, acc_o0, 0, 0, 0);
            acc_o1 = __builtin_amdgcn_mfma_f32_32x32x16_bf16(vf10, pb1, acc_o1, 0, 0, 0);
            acc_o0 = __builtin_amdgcn_mfma_f32_32x32x16_bf16(vf01, pb2, acc_o0, 0, 0, 0);
            acc_o1 = __builtin_amdgcn_mfma_f32_32x32x16_bf16(vf11, pb2, acc_o1, 0, 0, 0);
            __builtin_amdgcn_s_setprio(0);
        };

        // ---- prologue: reg-stage tiles 0,1 into buf 0 ----
        {
            bf16x8 k0 = *(const bf16x8*)(Ktg + (size_t)tid * 8);
            bf16x8 k1 = *(const bf16x8*)(Ktg + 2048 + (size_t)tid * 8);
            bf16x8 v0 = *(const bf16x8*)(Vtg + (size_t)tid * 8);
            bf16x8 v1 = *(const bf16x8*)(Vtg + 2048 + (size_t)tid * 8);
            *(bf16x8*)(kpool + tid * 8) = k0;
            *(bf16x8*)(kpool + 2048 + tid * 8) = k1;
            *(bf16x8*)(vpool + tid * 8) = v0;
            *(bf16x8*)(vpool + 2048 + tid * 8) = v1;
        }
        unsigned mw0 = bq[0];
        unsigned mw1 = bq[SEQ];

        int cur = 0;
        for (int t = 0; t < nt; t += 2) {
            __syncthreads();   // buf[cur] staged; prior reads of buf[cur^1] done

            const int tn0 = (t + 2 < nt) ? t + 2 : t;
            const int tn1 = (t + 3 < nt) ? t + 3 : t;
            bf16x8 sk0 = *(const bf16x8*)(Ktg + (size_t)tn0 * 2048 + tid * 8);
            bf16x8 sk1 = *(const bf16x8*)(Ktg + (size_t)tn1 * 2048 + tid * 8);
            bf16x8 sv0 = *(const bf16x8*)(Vtg + (size_t)tn0 * 2048 + tid * 8);
            bf16x8 sv1 = *(const bf16x8*)(Vtg + (size_t)tn1 * 2048 + tid * 8);
            unsigned nmw0 = bq[(size_t)tn0 * SEQ];
            unsigned nmw1 = bq[(size_t)tn1 * SEQ];

            body(kpool + cur * 4096,        vpool + cur * 4096,        mw0);
            body(kpool + cur * 4096 + 2048, vpool + cur * 4096 + 2048, mw1);

            *(bf16x8*)(kpool + (cur ^ 1) * 4096 + tid * 8)        = sk0;
            *(bf16x8*)(kpool + (cur ^ 1) * 4096 + 2048 + tid * 8) = sk1;
            *(bf16x8*)(vpool + (cur ^ 1) * 4096 + tid * 8)        = sv0;
            *(bf16x8*)(vpool + (cur ^ 1) * 4096 + 2048 + tid * 8) = sv1;

            mw0 = nmw0; mw1 = nmw1;
            cur ^= 1;
        }

        // ---- epilogue: per-wave normalize, bf16 stage in ALIASED LDS, write ----
        const float l_full = l_run + __shfl_xor(l_run, 32);
        const float invw = 1.f / l_full;   // diag always unmasked -> l_full > 0

        __syncthreads();   // all kv reads done -> safe to alias pool as oacc

        short (*oacc)[32][72] = (short (*)[32][72])pool;
        {
            unsigned short* orow = (unsigned short*)&oacc[wid][la][0];
            #pragma unroll
            for (int g = 0; g < 4; ++g) {
                const int d0 = 8 * g + 4 * h;
                unsigned w0 = cvt2(acc_o0[4 * g + 0] * invw, acc_o0[4 * g + 1] * invw);
                unsigned w1 = cvt2(acc_o0[4 * g + 2] * invw, acc_o0[4 * g + 3] * invw);
                unsigned w2 = cvt2(acc_o1[4 * g + 0] * invw, acc_o1[4 * g + 1] * invw);
                unsigned w3 = cvt2(acc_o1[4 * g + 2] * invw, acc_o1[4 * g + 3] * invw);
                *(unsigned*)&orow[d0]      = w0;
                *(unsigned*)&orow[d0 + 2]  = w1;
                *(unsigned*)&orow[d0 + 32] = w2;
                *(unsigned*)&orow[d0 + 34] = w3;
            }
        }
        __syncthreads();

        {
            const int q  = tid >> 3;
            const int dc = (tid & 7) * 8;
            #pragma unroll
            for (int k = 0; k < 4; ++k) {
                u32x4 pk = *(const u32x4*)&oacc[k][q][dc];
                float o[8];
                #pragma unroll
                for (int j = 0; j < 4; ++j) {
                    o[2 * j]     = __builtin_bit_cast(float, (pk[j] & 0xFFFFu) << 16);
                    o[2 * j + 1] = __builtin_bit_cast(float, pk[j] & 0xFFFF0000u);
                }
                float* op = Out + base + (size_t)(qg * 128 + k * 32 + q) * HD + dc;
                f32x4 o0v = {o[0], o[1], o[2], o[3]};
                f32x4 o1v = {o[4], o[5], o[6], o[7]};
                *(f32x4*)op       = o0v;
                *(f32x4*)(op + 4) = o1v;
            }
        }
        __syncthreads();   // oacc reads done before next item's prologue writes pool
    }
}

// ---------------- fallback (round-1 kernel) if ws too small ----------------
__global__ __launch_bounds__(256)
void attn_kernel(const float* __restrict__ Q, const float* __restrict__ K,
                 const float* __restrict__ V, const unsigned char* __restrict__ mask,
                 const int* __restrict__ flag, float* __restrict__ Out) {
    __shared__ short plds[4][16][40];
    const int esz  = *flag;
    const int bh   = blockIdx.y;
    const int wid  = threadIdx.x >> 6;
    const int lane = threadIdx.x & 63;
    const int l16  = lane & 15;
    const int hi   = lane >> 4;
    const int q0   = blockIdx.x * 64 + wid * 16;
    const size_t base = (size_t)bh * SEQ * HD;
    const float* Qb = Q + base;
    const float* Kb = K + base;
    const float* Vb = V + base;
    const unsigned int* mask32 = (const unsigned int*)mask;
    bf16x8 qf[2];
    {
        const float* qp = Qb + (size_t)(q0 + l16) * HD + hi * 8;
        f32x4 a0 = *(const f32x4*)(qp);
        f32x4 a1 = *(const f32x4*)(qp + 4);
        f32x4 a2 = *(const f32x4*)(qp + 32);
        f32x4 a3 = *(const f32x4*)(qp + 36);
        #pragma unroll
        for (int i = 0; i < 4; ++i) {
            qf[0][i] = f2bf(a0[i]); qf[0][4 + i] = f2bf(a1[i]);
            qf[1][i] = f2bf(a2[i]); qf[1][4 + i] = f2bf(a3[i]);
        }
    }
    f32x4 acc_o[4] = {f32x4{0,0,0,0}, f32x4{0,0,0,0}, f32x4{0,0,0,0}, f32x4{0,0,0,0}};
    float m_run[4], l_run[4];
    #pragma unroll
    for (int j = 0; j < 4; ++j) { m_run[j] = -__builtin_inff(); l_run[j] = 0.f; }
    const int kv_end = q0 + 16;
    for (int kv = 0; kv < kv_end; kv += 32) {
        f32x4 acc_s[2] = {f32x4{0,0,0,0}, f32x4{0,0,0,0}};
        #pragma unroll
        for (int t = 0; t < 2; ++t) {
            const float* kp = Kb + (size_t)(kv + 16 * t + l16) * HD + hi * 8;
            f32x4 b0 = *(const f32x4*)(kp);
            f32x4 b1 = *(const f32x4*)(kp + 4);
            f32x4 b2 = *(const f32x4*)(kp + 32);
            f32x4 b3 = *(const f32x4*)(kp + 36);
            bf16x8 kf0, kf1;
            #pragma unroll
            for (int i = 0; i < 4; ++i) {
                kf0[i] = f2bf(b0[i]); kf0[4 + i] = f2bf(b1[i]);
                kf1[i] = f2bf(b2[i]); kf1[4 + i] = f2bf(b3[i]);
            }
            acc_s[t] = __builtin_amdgcn_mfma_f32_16x16x32_bf16(qf[0], kf0, acc_s[t], 0, 0, 0);
            acc_s[t] = __builtin_amdgcn_mfma_f32_16x16x32_bf16(qf[1], kf1, acc_s[t], 0, 0, 0);
        }
        float s[2][4];
        #pragma unroll
        for (int t = 0; t < 2; ++t) {
            const int k = kv + 16 * t + l16;
            #pragma unroll
            for (int j = 0; j < 4; ++j) {
                const int qrow = q0 + hi * 4 + j;
                const size_t midx = (size_t)qrow * SEQ + k;
                const bool mv = (esz == 1) ? (mask[midx] != 0) : (mask32[midx] != 0);
                s[t][j] = mv ? acc_s[t][j] * SCALE : -__builtin_inff();
            }
        }
        float mnew[4], r[4];
        #pragma unroll
        for (int j = 0; j < 4; ++j) {
            float v = fmaxf(s[0][j], s[1][j]);
            #pragma unroll
            for (int off = 1; off < 16; off <<= 1) v = fmaxf(v, __shfl_xor(v, off));
            mnew[j] = fmaxf(m_run[j], v);
            r[j] = (m_run[j] > -__builtin_inff()) ? __expf(m_run[j] - mnew[j]) : 0.f;
        }
        float p[2][4];
        #pragma unroll
        for (int j = 0; j < 4; ++j) {
            float ps = 0.f;
            #pragma unroll
            for (int t = 0; t < 2; ++t) {
                p[t][j] = (s[t][j] > -__builtin_inff()) ? __expf(s[t][j] - mnew[j]) : 0.f;
                ps += p[t][j];
            }
            #pragma unroll
            for (int off = 1; off < 16; off <<= 1) ps += __shfl_xor(ps, off);
            l_run[j] = l_run[j] * r[j] + ps;
            m_run[j] = mnew[j];
            #pragma unroll
            for (int t2 = 0; t2 < 4; ++t2) acc_o[t2][j] *= r[j];
        }
        #pragma unroll
        for (int t = 0; t < 2; ++t)
            #pragma unroll
            for (int j = 0; j < 4; ++j)
                plds[wid][hi * 4 + j][16 * t + l16] = f2bf(p[t][j]);
        bf16x8 pa = *(bf16x8*)&plds[wid][l16][hi * 8];
        #pragma unroll
        for (int t2 = 0; t2 < 4; ++t2) {
            const float* vp = Vb + (size_t)(kv + hi * 8) * HD + 16 * t2 + l16;
            bf16x8 vf;
            #pragma unroll
            for (int i = 0; i < 8; ++i) vf[i] = f2bf(vp[(size_t)i * HD]);
            acc_o[t2] = __builtin_amdgcn_mfma_f32_16x16x32_bf16(pa, vf, acc_o[t2], 0, 0, 0);
        }
    }
    #pragma unroll
    for (int j = 0; j < 4; ++j) {
        const float inv = 1.f / l_run[j];
        const int qrow = q0 + hi * 4 + j;
        float* op = Out + base + (size_t)qrow * HD + l16;
        #pragma unroll
        for (int t2 = 0; t2 < 4; ++t2) op[16 * t2] = acc_o[t2][j] * inv;
    }
}

extern "C" void kernel_launch(void* const* d_in, const int* in_sizes, int n_in,
                              void* d_out, int out_size, void* d_ws, size_t ws_size,
                              hipStream_t stream) {
    const float* Q = (const float*)d_in[0];
    const float* K = (const float*)d_in[1];
    const float* V = (const float*)d_in[2];
    const unsigned char* mask = (const unsigned char*)d_in[3];

    const size_t bitsB = (size_t)SEQ * (SEQ / 32) * 4;          // 512 KB
    const size_t kvB   = (size_t)NBH * SEQ * HD * 2;            // 8 MB
    const size_t need  = bitsB + 2 * kvB + 256;                 // 16.5 MB

    if (ws_size >= need) {
        unsigned* bits = (unsigned*)d_ws;
        short* Kb = (short*)((char*)d_ws + bitsB);
        short* Vt = (short*)((char*)d_ws + bitsB + kvB);
        int* ctr  = (int*)((char*)d_ws + bitsB + 2 * kvB);

        prep_kernel<<<dim3(3584), dim3(256), 0, stream>>>(mask, in_sizes[3], K, V, bits, Kb, Vt, ctr);
        attn_persist_kernel<<<dim3(512), dim3(256), 0, stream>>>(Q, Kb, Vt, bits, ctr, (float*)d_out);
    } else {
        int* flag = (int*)d_ws;
        detect_mask_kernel<<<dim3(1), dim3(64), 0, stream>>>(mask, in_sizes[3], flag);
        attn_kernel<<<dim3(SEQ / 64, NBH), dim3(256), 0, stream>>>(Q, K, V, mask, flag, (float*)d_out);
    }
}

// Round 21
// 53.488 us; speedup vs baseline: 1.2856x; 1.2856x over previous
//
#include <hip/hip_runtime.h>
#include <hip/hip_bf16.h>

#define SEQ 2048
#define HD 64
#define NBH 32
#define SCALE 0.125f
#define QSC 0.18033688011112042f   // 0.125 * log2(e)  -> softmax in exp2 domain

typedef __attribute__((ext_vector_type(4)))  float    f32x4;
typedef __attribute__((ext_vector_type(16))) float    f32x16;
typedef __attribute__((ext_vector_type(8)))  short    bf16x8;
typedef __attribute__((ext_vector_type(4)))  unsigned u32x4;

__device__ inline short f2bf(float f) {
    unsigned u = __builtin_bit_cast(unsigned, f);
    unsigned r = u + 0x7FFFu + ((u >> 16) & 1u);
    return (short)(r >> 16);
}

__device__ inline unsigned cvt2(float lo, float hi) {
    unsigned d;
    asm("v_cvt_pk_bf16_f32 %0, %1, %2" : "=v"(d) : "v"(lo), "v"(hi));
    return d;
}

// Detect mask element size (1-byte bool vs 4-byte), for the r1 fallback path only.
__global__ void detect_mask_kernel(const unsigned char* __restrict__ m, int n, int* flag) {
    if (threadIdx.x == 0) *flag = (m[n - 1] != 0) ? 1 : 4;
}

// Fused prepass (validated r12/r16; mask-width detect inlined).
// [0,512):    bitpack mask -> bitsT[64][2048]
// [512,2560): K fp32 -> bf16 granule-major tiles (wave frag = stride-16B linear)
// [2560,3584): V fp32 -> Vt granule-major with swap23 k-relabel
__global__ __launch_bounds__(256)
void prep_kernel(const unsigned char* __restrict__ m, int mn,
                 const float* __restrict__ K, const float* __restrict__ V,
                 unsigned* __restrict__ bits, short* __restrict__ Kb,
                 short* __restrict__ Vt) {
    __shared__ short t[64][65];
    const int b = blockIdx.x, tid = threadIdx.x;
    if (b < 512) {
        const bool e1 = (m[mn - 1] != 0);
        const int idx = b * 256 + tid;
        const int row = idx >> 6, w = idx & 63;
        const size_t base = (size_t)row * SEQ + w * 32;
        unsigned word = 0;
        if (e1) {
            #pragma unroll
            for (int i = 0; i < 32; ++i) word |= (unsigned)(m[base + i] != 0) << i;
        } else {
            const unsigned* m32 = (const unsigned*)m;
            #pragma unroll
            for (int i = 0; i < 32; ++i) word |= (unsigned)(m32[base + i] != 0) << i;
        }
        bits[(size_t)w * SEQ + row] = word;
    } else if (b < 2560) {
        const int g = (b - 512) * 256 + tid;     // granule index
        const size_t i = (size_t)g * 8;
        f32x4 a = *(const f32x4*)(K + i);
        f32x4 c = *(const f32x4*)(K + i + 4);
        bf16x8 o;
        #pragma unroll
        for (int j = 0; j < 4; ++j) { o[j] = f2bf(a[j]); o[4 + j] = f2bf(c[j]); }
        const int row = g >> 3;
        const int c8  = g & 7;
        const int bh  = row >> 11;
        const int r   = row & 2047;
        const int tt  = r >> 5;
        const int la  = r & 31;
        *(bf16x8*)(Kb + ((size_t)bh * 64 + tt) * 2048 + (c8 * 32 + la) * 8) = o;
    } else {
        const int bb = b - 2560;
        const int s0 = (bb & 31) * 64, bh = bb >> 5;
        const float* Vb = V + (size_t)bh * SEQ * HD;
        const int sr = tid >> 6, d = tid & 63;
        #pragma unroll
        for (int i = 0; i < 16; ++i) {
            const int s = i * 4 + sr;
            t[s][d] = f2bf(Vb[(size_t)(s0 + s) * HD + d]);
        }
        __syncthreads();
        short* o = Vt + (size_t)bh * HD * SEQ;
        const int dr = tid >> 6, sl = tid & 63;
        #pragma unroll
        for (int i = 0; i < 16; ++i) {
            const int dd = i * 4 + dr;
            const int s = s0 + sl;
            const int k = s & 31;
            const int p = (k & ~12) | ((k & 8) >> 1) | ((k & 4) << 1);   // swap bits 2,3
            const int mm = ((dd >> 5) << 1) | (p >> 4);
            const int hh = (p >> 3) & 1;
            o[(size_t)(s >> 5) * 2048 + ((mm * 2 + hh) * 32 + (dd & 31)) * 8 + (p & 7)] = t[sl][dd];
        }
    }
}

// ================= shared-KV monolith, 2-tile steps + aliased pool (r19 FINAL) =================
// Best measured configuration (53.4us total). 512 blocks, static balanced
// pairing (id<256: qg=15-(id>>5), else qg=(id-256)>>5); bh=id&31 keeps
// same-bh blocks on one XCD (L2 locality: FETCH 17.5MB; r20's dynamic
// stealing destroyed this -> 48MB, +29% time). 2-tile double-buffered
// shared-KV staging, fixed-scale softmax, zero-cross-lane P-pack, aliased
// 32KB pool, dependent 4-MFMA QK chain.
__global__ __launch_bounds__(256, 2)
void attn_shared2_kernel(const float* __restrict__ Q, const short* __restrict__ Kb,
                         const short* __restrict__ Vt, const unsigned* __restrict__ bitsT,
                         float* __restrict__ Out) {
    __shared__ __align__(16) short pool[16384];   // 32KB: [k 2buf x 2tile][v 2buf x 2tile]
    short* kpool = pool;              // buf stride 4096, tile stride 2048
    short* vpool = pool + 8192;

    const int id   = blockIdx.x;
    const int bh   = id & 31;
    const int qg   = (id < 256) ? (15 - (id >> 5)) : ((id - 256) >> 5);
    const int tid  = threadIdx.x;
    const int wid  = tid >> 6;
    const int lane = tid & 63;
    const int la   = lane & 31;
    const int h    = lane >> 5;
    const int q0w  = qg * 128 + wid * 32;
    const int nt   = qg * 4 + 4;              // multiple of 4
    const size_t base = (size_t)bh * SEQ * HD;

    // Q as MFMA B-operand: col=q=la, k-elem i of chunk j -> d = j*16 + h*8 + i
    bf16x8 qf[4];
    {
        const float* qp = Q + base + (size_t)(q0w + la) * HD + h * 8;
        #pragma unroll
        for (int j = 0; j < 4; ++j) {
            f32x4 a0 = *(const f32x4*)(qp + j * 16);
            f32x4 a1 = *(const f32x4*)(qp + j * 16 + 4);
            #pragma unroll
            for (int i = 0; i < 4; ++i) {
                qf[j][i]     = f2bf(a0[i] * QSC);
                qf[j][4 + i] = f2bf(a1[i] * QSC);
            }
        }
    }

    f32x16 acc_o0 = {0,0,0,0,0,0,0,0,0,0,0,0,0,0,0,0};
    f32x16 acc_o1 = {0,0,0,0,0,0,0,0,0,0,0,0,0,0,0,0};
    float l_run = 0.f;

    const short* Ktg = Kb + (size_t)bh * 64 * 2048;
    const short* Vtg = Vt + (size_t)bh * 64 * 2048;
    const unsigned* bq = bitsT + q0w + la;
    const int bp = 4 * h;

    auto body = [&](const short* kb, const short* vb, unsigned mwx) {
        bf16x8 kfa = *(const bf16x8*)(kb + lane * 8);
        bf16x8 kfb = *(const bf16x8*)(kb + 512 + lane * 8);
        bf16x8 kfc = *(const bf16x8*)(kb + 1024 + lane * 8);
        bf16x8 kfd = *(const bf16x8*)(kb + 1536 + lane * 8);
        bf16x8 vf00 = *(const bf16x8*)(vb + lane * 8);
        bf16x8 vf01 = *(const bf16x8*)(vb + 512 + lane * 8);
        bf16x8 vf10 = *(const bf16x8*)(vb + 1024 + lane * 8);
        bf16x8 vf11 = *(const bf16x8*)(vb + 1536 + lane * 8);

        // single dependent 4-MFMA QK chain (accumulate chaining is
        // throughput-rate on the matrix pipe)
        f32x16 s = {0,0,0,0,0,0,0,0,0,0,0,0,0,0,0,0};
        __builtin_amdgcn_s_setprio(1);
        s = __builtin_amdgcn_mfma_f32_32x32x16_bf16(kfa, qf[0], s, 0, 0, 0);
        s = __builtin_amdgcn_mfma_f32_32x32x16_bf16(kfb, qf[1], s, 0, 0, 0);
        s = __builtin_amdgcn_mfma_f32_32x32x16_bf16(kfc, qf[2], s, 0, 0, 0);
        s = __builtin_amdgcn_mfma_f32_32x32x16_bf16(kfd, qf[3], s, 0, 0, 0);
        __builtin_amdgcn_s_setprio(0);

        #pragma unroll
        for (int r = 0; r < 16; ++r) {
            float e = __builtin_amdgcn_exp2f(s[r]);
            s[r] = ((mwx >> (bp + (r & 3) + 8 * (r >> 2))) & 1u) ? e : 0.f;
        }
        float ps = ((s[0] + s[1]) + (s[2] + s[3])) + ((s[4] + s[5]) + (s[6] + s[7]));
        ps += ((s[8] + s[9]) + (s[10] + s[11])) + ((s[12] + s[13]) + (s[14] + s[15]));
        l_run += ps;

        u32x4 t1 = {cvt2(s[0], s[1]),  cvt2(s[2], s[3]),
                    cvt2(s[4], s[5]),  cvt2(s[6], s[7])};
        u32x4 t2 = {cvt2(s[8], s[9]),  cvt2(s[10], s[11]),
                    cvt2(s[12], s[13]), cvt2(s[14], s[15])};
        bf16x8 pb1 = __builtin_bit_cast(bf16x8, t1);
        bf16x8 pb2 = __builtin_bit_cast(bf16x8, t2);

        __builtin_amdgcn_s_setprio(1);
        acc_o0 = __builtin_amdgcn_mfma_f32_32x32x16_bf16(vf00, pb1, acc_o0, 0, 0, 0);
        acc_o1 = __builtin_amdgcn_mfma_f32_32x32x16_bf16(vf10, pb1, acc_o1, 0, 0, 0);
        acc_o0 = __builtin_amdgcn_mfma_f32_32x32x16_bf16(vf01, pb2, acc_o0, 0, 0, 0);
        acc_o1 = __builtin_amdgcn_mfma_f32_32x32x16_bf16(vf11, pb2, acc_o1, 0, 0, 0);
        __builtin_amdgcn_s_setprio(0);
    };

    // ---- prologue: reg-stage tiles 0,1 into buf 0 ----
    {
        bf16x8 k0 = *(const bf16x8*)(Ktg + (size_t)tid * 8);
        bf16x8 k1 = *(const bf16x8*)(Ktg + 2048 + (size_t)tid * 8);
        bf16x8 v0 = *(const bf16x8*)(Vtg + (size_t)tid * 8);
        bf16x8 v1 = *(const bf16x8*)(Vtg + 2048 + (size_t)tid * 8);
        *(bf16x8*)(kpool + tid * 8) = k0;
        *(bf16x8*)(kpool + 2048 + tid * 8) = k1;
        *(bf16x8*)(vpool + tid * 8) = v0;
        *(bf16x8*)(vpool + 2048 + tid * 8) = v1;
    }
    unsigned mw0 = bq[0];
    unsigned mw1 = bq[SEQ];

    int cur = 0;
    for (int t = 0; t < nt; t += 2) {
        __syncthreads();   // buf[cur] staged; prior reads of buf[cur^1] done

        // ---- prefetch tiles t+2, t+3 to regs + masks (clamped on last iter) ----
        const int tn0 = (t + 2 < nt) ? t + 2 : t;
        const int tn1 = (t + 3 < nt) ? t + 3 : t;
        bf16x8 sk0 = *(const bf16x8*)(Ktg + (size_t)tn0 * 2048 + tid * 8);
        bf16x8 sk1 = *(const bf16x8*)(Ktg + (size_t)tn1 * 2048 + tid * 8);
        bf16x8 sv0 = *(const bf16x8*)(Vtg + (size_t)tn0 * 2048 + tid * 8);
        bf16x8 sv1 = *(const bf16x8*)(Vtg + (size_t)tn1 * 2048 + tid * 8);
        unsigned nmw0 = bq[(size_t)tn0 * SEQ];
        unsigned nmw1 = bq[(size_t)tn1 * SEQ];

        // ---- compute tiles t, t+1 ----
        body(kpool + cur * 4096,        vpool + cur * 4096,        mw0);
        body(kpool + cur * 4096 + 2048, vpool + cur * 4096 + 2048, mw1);

        // ---- write staged regs into the other buffer ----
        *(bf16x8*)(kpool + (cur ^ 1) * 4096 + tid * 8)        = sk0;
        *(bf16x8*)(kpool + (cur ^ 1) * 4096 + 2048 + tid * 8) = sk1;
        *(bf16x8*)(vpool + (cur ^ 1) * 4096 + tid * 8)        = sv0;
        *(bf16x8*)(vpool + (cur ^ 1) * 4096 + 2048 + tid * 8) = sv1;

        mw0 = nmw0; mw1 = nmw1;
        cur ^= 1;
    }

    // ---- epilogue: per-wave normalize, bf16 stage in ALIASED LDS, coalesced write ----
    const float l_full = l_run + __shfl_xor(l_run, 32);
    const float invw = 1.f / l_full;   // diag always unmasked -> l_full > 0

    __syncthreads();   // all kv reads done -> safe to alias pool as oacc

    short (*oacc)[32][72] = (short (*)[32][72])pool;
    {
        unsigned short* orow = (unsigned short*)&oacc[wid][la][0];
        #pragma unroll
        for (int g = 0; g < 4; ++g) {
            const int d0 = 8 * g + 4 * h;
            unsigned w0 = cvt2(acc_o0[4 * g + 0] * invw, acc_o0[4 * g + 1] * invw);
            unsigned w1 = cvt2(acc_o0[4 * g + 2] * invw, acc_o0[4 * g + 3] * invw);
            unsigned w2 = cvt2(acc_o1[4 * g + 0] * invw, acc_o1[4 * g + 1] * invw);
            unsigned w3 = cvt2(acc_o1[4 * g + 2] * invw, acc_o1[4 * g + 3] * invw);
            *(unsigned*)&orow[d0]      = w0;
            *(unsigned*)&orow[d0 + 2]  = w1;
            *(unsigned*)&orow[d0 + 32] = w2;
            *(unsigned*)&orow[d0 + 34] = w3;
        }
    }
    __syncthreads();

    {
        const int q  = tid >> 3;
        const int dc = (tid & 7) * 8;
        #pragma unroll
        for (int k = 0; k < 4; ++k) {
            u32x4 pk = *(const u32x4*)&oacc[k][q][dc];
            float o[8];
            #pragma unroll
            for (int j = 0; j < 4; ++j) {
                o[2 * j]     = __builtin_bit_cast(float, (pk[j] & 0xFFFFu) << 16);
                o[2 * j + 1] = __builtin_bit_cast(float, pk[j] & 0xFFFF0000u);
            }
            float* op = Out + base + (size_t)(qg * 128 + k * 32 + q) * HD + dc;
            f32x4 o0v = {o[0], o[1], o[2], o[3]};
            f32x4 o1v = {o[4], o[5], o[6], o[7]};
            *(f32x4*)op       = o0v;
            *(f32x4*)(op + 4) = o1v;
        }
    }
}

// ---------------- fallback (round-1 kernel) if ws too small ----------------
__global__ __launch_bounds__(256)
void attn_kernel(const float* __restrict__ Q, const float* __restrict__ K,
                 const float* __restrict__ V, const unsigned char* __restrict__ mask,
                 const int* __restrict__ flag, float* __restrict__ Out) {
    __shared__ short plds[4][16][40];
    const int esz  = *flag;
    const int bh   = blockIdx.y;
    const int wid  = threadIdx.x >> 6;
    const int lane = threadIdx.x & 63;
    const int l16  = lane & 15;
    const int hi   = lane >> 4;
    const int q0   = blockIdx.x * 64 + wid * 16;
    const size_t base = (size_t)bh * SEQ * HD;
    const float* Qb = Q + base;
    const float* Kb = K + base;
    const float* Vb = V + base;
    const unsigned int* mask32 = (const unsigned int*)mask;
    bf16x8 qf[2];
    {
        const float* qp = Qb + (size_t)(q0 + l16) * HD + hi * 8;
        f32x4 a0 = *(const f32x4*)(qp);
        f32x4 a1 = *(const f32x4*)(qp + 4);
        f32x4 a2 = *(const f32x4*)(qp + 32);
        f32x4 a3 = *(const f32x4*)(qp + 36);
        #pragma unroll
        for (int i = 0; i < 4; ++i) {
            qf[0][i] = f2bf(a0[i]); qf[0][4 + i] = f2bf(a1[i]);
            qf[1][i] = f2bf(a2[i]); qf[1][4 + i] = f2bf(a3[i]);
        }
    }
    f32x4 acc_o[4] = {f32x4{0,0,0,0}, f32x4{0,0,0,0}, f32x4{0,0,0,0}, f32x4{0,0,0,0}};
    float m_run[4], l_run[4];
    #pragma unroll
    for (int j = 0; j < 4; ++j) { m_run[j] = -__builtin_inff(); l_run[j] = 0.f; }
    const int kv_end = q0 + 16;
    for (int kv = 0; kv < kv_end; kv += 32) {
        f32x4 acc_s[2] = {f32x4{0,0,0,0}, f32x4{0,0,0,0}};
        #pragma unroll
        for (int t = 0; t < 2; ++t) {
            const float* kp = Kb + (size_t)(kv + 16 * t + l16) * HD + hi * 8;
            f32x4 b0 = *(const f32x4*)(kp);
            f32x4 b1 = *(const f32x4*)(kp + 4);
            f32x4 b2 = *(const f32x4*)(kp + 32);
            f32x4 b3 = *(const f32x4*)(kp + 36);
            bf16x8 kf0, kf1;
            #pragma unroll
            for (int i = 0; i < 4; ++i) {
                kf0[i] = f2bf(b0[i]); kf0[4 + i] = f2bf(b1[i]);
                kf1[i] = f2bf(b2[i]); kf1[4 + i] = f2bf(b3[i]);
            }
            acc_s[t] = __builtin_amdgcn_mfma_f32_16x16x32_bf16(qf[0], kf0, acc_s[t], 0, 0, 0);
            acc_s[t] = __builtin_amdgcn_mfma_f32_16x16x32_bf16(qf[1], kf1, acc_s[t], 0, 0, 0);
        }
        float s[2][4];
        #pragma unroll
        for (int t = 0; t < 2; ++t) {
            const int k = kv + 16 * t + l16;
            #pragma unroll
            for (int j = 0; j < 4; ++j) {
                const int qrow = q0 + hi * 4 + j;
                const size_t midx = (size_t)qrow * SEQ + k;
                const bool mv = (esz == 1) ? (mask[midx] != 0) : (mask32[midx] != 0);
                s[t][j] = mv ? acc_s[t][j] * SCALE : -__builtin_inff();
            }
        }
        float mnew[4], r[4];
        #pragma unroll
        for (int j = 0; j < 4; ++j) {
            float v = fmaxf(s[0][j], s[1][j]);
            #pragma unroll
            for (int off = 1; off < 16; off <<= 1) v = fmaxf(v, __shfl_xor(v, off));
            mnew[j] = fmaxf(m_run[j], v);
            r[j] = (m_run[j] > -__builtin_inff()) ? __expf(m_run[j] - mnew[j]) : 0.f;
        }
        float p[2][4];
        #pragma unroll
        for (int j = 0; j < 4; ++j) {
            float ps = 0.f;
            #pragma unroll
            for (int t = 0; t < 2; ++t) {
                p[t][j] = (s[t][j] > -__builtin_inff()) ? __expf(s[t][j] - mnew[j]) : 0.f;
                ps += p[t][j];
            }
            #pragma unroll
            for (int off = 1; off < 16; off <<= 1) ps += __shfl_xor(ps, off);
            l_run[j] = l_run[j] * r[j] + ps;
            m_run[j] = mnew[j];
            #pragma unroll
            for (int t2 = 0; t2 < 4; ++t2) acc_o[t2][j] *= r[j];
        }
        #pragma unroll
        for (int t = 0; t < 2; ++t)
            #pragma unroll
            for (int j = 0; j < 4; ++j)
                plds[wid][hi * 4 + j][16 * t + l16] = f2bf(p[t][j]);
        bf16x8 pa = *(bf16x8*)&plds[wid][l16][hi * 8];
        #pragma unroll
        for (int t2 = 0; t2 < 4; ++t2) {
            const float* vp = Vb + (size_t)(kv + hi * 8) * HD + 16 * t2 + l16;
            bf16x8 vf;
            #pragma unroll
            for (int i = 0; i < 8; ++i) vf[i] = f2bf(vp[(size_t)i * HD]);
            acc_o[t2] = __builtin_amdgcn_mfma_f32_16x16x32_bf16(pa, vf, acc_o[t2], 0, 0, 0);
        }
    }
    #pragma unroll
    for (int j = 0; j < 4; ++j) {
        const float inv = 1.f / l_run[j];
        const int qrow = q0 + hi * 4 + j;
        float* op = Out + base + (size_t)qrow * HD + l16;
        #pragma unroll
        for (int t2 = 0; t2 < 4; ++t2) op[16 * t2] = acc_o[t2][j] * inv;
    }
}

extern "C" void kernel_launch(void* const* d_in, const int* in_sizes, int n_in,
                              void* d_out, int out_size, void* d_ws, size_t ws_size,
                              hipStream_t stream) {
    const float* Q = (const float*)d_in[0];
    const float* K = (const float*)d_in[1];
    const float* V = (const float*)d_in[2];
    const unsigned char* mask = (const unsigned char*)d_in[3];

    const size_t bitsB = (size_t)SEQ * (SEQ / 32) * 4;          // 512 KB
    const size_t kvB   = (size_t)NBH * SEQ * HD * 2;            // 8 MB
    const size_t need  = bitsB + 2 * kvB + 256;                 // 16.5 MB

    if (ws_size >= need) {
        unsigned* bits = (unsigned*)d_ws;
        short* Kb = (short*)((char*)d_ws + bitsB);
        short* Vt = (short*)((char*)d_ws + bitsB + kvB);

        prep_kernel<<<dim3(3584), dim3(256), 0, stream>>>(mask, in_sizes[3], K, V, bits, Kb, Vt);
        attn_shared2_kernel<<<dim3(512), dim3(256), 0, stream>>>(Q, Kb, Vt, bits, (float*)d_out);
    } else {
        int* flag = (int*)d_ws;
        detect_mask_kernel<<<dim3(1), dim3(64), 0, stream>>>(mask, in_sizes[3], flag);
        attn_kernel<<<dim3(SEQ / 64, NBH), dim3(256), 0, stream>>>(Q, K, V, mask, flag, (float*)d_out);
    }
}